// Round 14
// baseline (77.070 us; speedup 1.0000x reference)
//
#include <hip/hip_runtime.h>

#define NB 4
#define NCI 64
#define NCO 64
#define PLANE 65536

// workspace offsets (in floats)
#define OF_COS 0
#define OF_SIN 256
#define OF_TW  512                      // [30][256] k45 trig (ky=1..15 cos/sin)
#define OF_TK1 8192                     // [128][32] stage-1 trig: per w, 16 cos | 16 sin
#define OF_XS_RE (16384 + 32*PLANE)
#define OF_XS_IM (OF_XS_RE + PLANE)
#define OF_O1_RE (OF_XS_IM + PLANE)
#define OF_O1_IM (OF_O1_RE + PLANE)
#define OF_O2_RE (OF_O1_IM + PLANE)
#define OF_O2_IM (OF_O2_RE + PLANE)

// grid 47: block 0 -> cos/sin; 1..30 -> TW rows; 31..46 -> TK1 table
__global__ __launch_bounds__(256) void k0_init(float* __restrict__ ws) {
  const int t = threadIdx.x, b = blockIdx.x;
  const double TP = 6.283185307179586;
  if (b == 0) {
    double a = TP * t / 256.0;
    ws[OF_COS + t] = (float)cos(a);
    ws[OF_SIN + t] = (float)sin(a);
  } else if (b < 31) {
    const int p = b - 1;              // 0..29
    const int ky = (p >> 1) + 1;
    double a = TP * ((ky * t) & 255) / 256.0;
    ws[OF_TW + p*256 + t] = (p & 1) ? (float)sin(a) : (float)cos(a);
  } else {
    const int idx = (b - 31)*256 + t; // 0..4095
    const int w = idx >> 5, j = idx & 31;
    double v;
    if (j < 16) v =  cos(TP * ((j * w) & 255) / 256.0);
    else        v =  sin(TP * (((j - 16) * w) & 255) / 256.0);
    ws[OF_TK1 + idx] = (float)v;
  }
}

// Fused stage 1+2, ONE barrier, NO x-transpose.
// Phase A: thread = one row; stream x[row][w],x[row][w+128] from global
//   (lane=row -> clean L1 line reuse), fold in-register, trig via the
//   wave-uniform Tk table (scalarizes to s_load / constant cache).
//   16 ky x 2 FMA per folded w; 32 independent accumulators.
// Phase B: h-DFT per (kx,ky) thread with fp32 rotation chain over the
//   [32][260] LDS tile written by phase A.
__global__ __launch_bounds__(256) void k12_dft(const float* __restrict__ x,
                                               float* __restrict__ ws) {
  __shared__ float L[32*260];
  const int t = threadIdx.x, img = blockIdx.x;
  const float* xr = x + (size_t)img*65536 + (size_t)t*256;
  const float* Tk = ws + OF_TK1;

  float re[16], im[16];
#pragma unroll
  for (int j = 0; j < 16; ++j) { re[j] = 0.f; im[j] = 0.f; }

#pragma unroll 2
  for (int wb = 0; wb < 128; wb += 4) {
    const float4 lo = *(const float4*)(xr + wb);
    const float4 hi = *(const float4*)(xr + 128 + wb);
    const float xe[4] = {lo.x+hi.x, lo.y+hi.y, lo.z+hi.z, lo.w+hi.w};
    const float xo[4] = {lo.x-hi.x, lo.y-hi.y, lo.z-hi.z, lo.w-hi.w};
#pragma unroll
    for (int i = 0; i < 4; ++i) {
      const float* tw = Tk + (wb + i)*32;   // wave-uniform address -> s_load
#pragma unroll
      for (int j = 0; j < 16; ++j) {
        const float xs = (j & 1) ? xo[i] : xe[i];
        re[j] += xs * tw[j];
        im[j] -= xs * tw[16 + j];
      }
    }
  }

  // deposit row outputs: plane j, row t (lanes consecutive -> conflict-free)
#pragma unroll
  for (int j = 0; j < 16; ++j) {
    L[j*260 + t]        = re[j];
    L[(16 + j)*260 + t] = im[j];
  }
  __syncthreads();

  // ---- phase B: h-DFT ----
  const int kx = t >> 4, ky = t & 15;
  const float cdk = ws[OF_COS + kx];
  const float sdk = ws[OF_SIN + kx];
  float c = 1.f, s = 0.f, arr = 0.f, aii = 0.f;
  const int be = ky*260, bo = (16 + ky)*260;
#pragma unroll 4
  for (int hq = 0; hq < 64; ++hq) {
    const float4 xr4 = *(const float4*)&L[be + hq*4];
    const float4 xi4 = *(const float4*)&L[bo + hq*4];
    {
      arr += xr4.x*c + xi4.x*s;  aii += xi4.x*c - xr4.x*s;
      const float nc = c*cdk - s*sdk, ns = s*cdk + c*sdk; c = nc; s = ns;
    }
    {
      arr += xr4.y*c + xi4.y*s;  aii += xi4.y*c - xr4.y*s;
      const float nc = c*cdk - s*sdk, ns = s*cdk + c*sdk; c = nc; s = ns;
    }
    {
      arr += xr4.z*c + xi4.z*s;  aii += xi4.z*c - xr4.z*s;
      const float nc = c*cdk - s*sdk, ns = s*cdk + c*sdk; c = nc; s = ns;
    }
    {
      arr += xr4.w*c + xi4.w*s;  aii += xi4.w*c - xr4.w*s;
      const float nc = c*cdk - s*sdk, ns = s*cdk + c*sdk; c = nc; s = ns;
    }
  }
  ws[OF_XS_RE + img*256 + t] = arr;
  ws[OF_XS_IM + img*256 + t] = aii;
}

// Stage 3: o1/o2[b,o,m] = sum_i xs[b,i,m] * (wr + i wi)[i,o,m]
__global__ __launch_bounds__(256) void k3_mix(const float* __restrict__ w1r,
    const float* __restrict__ w1i, const float* __restrict__ w2r,
    const float* __restrict__ w2i, float* __restrict__ ws) {
  const int o  = blockIdx.x;     // 0..63
  const int mc = blockIdx.y;     // 0..3
  const int t  = threadIdx.x;    // 256
  const int b  = t >> 6;
  const int m  = (mc << 6) + (t & 63);
  const float* xsr = ws + OF_XS_RE;
  const float* xsi = ws + OF_XS_IM;
  float a1r=0.f, a1i=0.f, a2r=0.f, a2i=0.f;
#pragma unroll 4
  for (int i = 0; i < NCI; ++i) {
    const float xr = xsr[((b*NCI + i) << 8) + m];
    const float xi = xsi[((b*NCI + i) << 8) + m];
    const int wi = ((i*NCO + o) << 8) + m;
    const float p = w1r[wi], q = w1i[wi], u = w2r[wi], v = w2i[wi];
    a1r += xr*p - xi*q;
    a1i += xr*q + xi*p;
    a2r += xr*u - xi*v;
    a2i += xr*v + xi*u;
  }
  const int oi = ((b*NCO + o) << 8) + m;
  ws[OF_O1_RE + oi] = a1r;
  ws[OF_O1_IM + oi] = a1i;
  ws[OF_O2_RE + oi] = a2r;
  ws[OF_O2_IM + oi] = a2i;
}

// Fused stage 4+5 (R13-verbatim, best measured).
__global__ __launch_bounds__(256) void k45_idft(const float* __restrict__ ws,
                                                float* __restrict__ out) {
  __shared__ __align__(16) float o1r[256], o1i[256], o2r[256], o2i[256];
  __shared__ float cst[256], snt[256];
  __shared__ __align__(16) float Sr[64][20], Si[64][20];
  const int t  = threadIdx.x;
  const int bo = blockIdx.x >> 2;
  const int hc = blockIdx.x & 3;

  o1r[t] = ws[OF_O1_RE + bo*256 + t];
  o1i[t] = ws[OF_O1_IM + bo*256 + t];
  o2r[t] = ws[OF_O2_RE + bo*256 + t];
  o2i[t] = ws[OF_O2_IM + bo*256 + t];
  cst[t] = ws[OF_COS + t];
  snt[t] = ws[OF_SIN + t];

  const int wl = t & 31;
  const float* Tw = ws + OF_TW;
  float c[15], s[15], c2[15], s2[15];
#pragma unroll
  for (int k = 0; k < 15; ++k) {
    c[k] = Tw[(2*k)*256 + wl];
    s[k] = Tw[(2*k+1)*256 + wl];
  }
  {
    const float R = 0.70710678118654752f;
#pragma unroll
    for (int k = 0; k < 15; ++k) {
      const int r8 = (k + 1) & 7;
      switch (r8) {
        case 0: c2[k] =  c[k];            s2[k] =  s[k];            break;
        case 1: c2[k] = (c[k]-s[k])*R;    s2[k] = (s[k]+c[k])*R;    break;
        case 2: c2[k] = -s[k];            s2[k] =  c[k];            break;
        case 3: c2[k] = -(c[k]+s[k])*R;   s2[k] = (c[k]-s[k])*R;    break;
        case 4: c2[k] = -c[k];            s2[k] = -s[k];            break;
        case 5: c2[k] = (s[k]-c[k])*R;    s2[k] = -(c[k]+s[k])*R;   break;
        case 6: c2[k] =  s[k];            s2[k] = -c[k];            break;
        default:c2[k] = (c[k]+s[k])*R;    s2[k] = (s[k]-c[k])*R;    break;
      }
    }
  }
  __syncthreads();

  // ---- phase A ----
  {
    const int hl = t >> 2, kq = t & 3;
    const int h  = hc*64 + hl;
    const float chh = cst[h], shh = snt[h];
    float c1 = 1.f, s1 = 0.f;
    const int m2i = (240 * h) & 255;
    float cB = cst[m2i], sB = snt[m2i];
    float4 sr = {0.f,0.f,0.f,0.f}, si = {0.f,0.f,0.f,0.f};
    for (int j = 0; j < 16; ++j) {
      const float4 r1 = *(const float4*)&o1r[j*16 + kq*4];
      const float4 i1 = *(const float4*)&o1i[j*16 + kq*4];
      const float4 r2 = *(const float4*)&o2r[j*16 + kq*4];
      const float4 i2 = *(const float4*)&o2i[j*16 + kq*4];
      sr.x += r1.x*c1 - i1.x*s1 + r2.x*cB - i2.x*sB;
      si.x += r1.x*s1 + i1.x*c1 + r2.x*sB + i2.x*cB;
      sr.y += r1.y*c1 - i1.y*s1 + r2.y*cB - i2.y*sB;
      si.y += r1.y*s1 + i1.y*c1 + r2.y*sB + i2.y*cB;
      sr.z += r1.z*c1 - i1.z*s1 + r2.z*cB - i2.z*sB;
      si.z += r1.z*s1 + i1.z*c1 + r2.z*sB + i2.z*cB;
      sr.w += r1.w*c1 - i1.w*s1 + r2.w*cB - i2.w*sB;
      si.w += r1.w*s1 + i1.w*c1 + r2.w*sB + i2.w*cB;
      const float n1c = c1*chh - s1*shh, n1s = s1*chh + c1*shh;
      const float n2c = cB*chh - sB*shh, n2s = sB*chh + cB*shh;
      c1 = n1c; s1 = n1s; cB = n2c; sB = n2s;
    }
    *(float4*)&Sr[hl][kq*4] = sr;
    *(float4*)&Si[hl][kq*4] = si;
  }
  __syncthreads();

  // ---- phase B: row-paired, radix-4 butterfly x2 trig sets ----
  const int half = (t >> 5) & 1;
  const int wv = t >> 6;
  const float scale = 2.0f / 65536.0f;
  const size_t tilebase = ((size_t)bo*256 + hc*64) * 256;
#pragma unroll 2
  for (int pr = 0; pr < 8; ++pr) {
    const int hl = wv*16 + pr*2 + half;
    const float4 a0 = *(const float4*)&Sr[hl][0];
    const float4 a1 = *(const float4*)&Sr[hl][4];
    const float4 a2 = *(const float4*)&Sr[hl][8];
    const float4 a3 = *(const float4*)&Sr[hl][12];
    const float4 b0 = *(const float4*)&Si[hl][0];
    const float4 b1 = *(const float4*)&Si[hl][4];
    const float4 b2 = *(const float4*)&Si[hl][8];
    const float4 b3 = *(const float4*)&Si[hl][12];
    const float re[16] = {a0.x,a0.y,a0.z,a0.w, a1.x,a1.y,a1.z,a1.w,
                          a2.x,a2.y,a2.z,a2.w, a3.x,a3.y,a3.z,a3.w};
    const float im[16] = {b0.x,b0.y,b0.z,b0.w, b1.x,b1.y,b1.z,b1.w,
                          b2.x,b2.y,b2.z,b2.w, b3.x,b3.y,b3.z,b3.w};
    const size_t ob = tilebase + (size_t)hl*256;

#pragma unroll
    for (int g = 0; g < 2; ++g) {
      const float* cc = g ? c2 : c;
      const float* ss = g ? s2 : s;
      float PA = 0.5f * re[0];
      float PB = 0.f, PC = 0.f, PD = 0.f, QB = 0.f, QD = 0.f;
#pragma unroll
      for (int k = 0; k < 15; ++k) {
        const int ky = k + 1;
        const float R = re[ky], I = im[ky];
        const int cls = ky & 3;
        if (cls == 0)      PA += R*cc[k] - I*ss[k];
        else if (cls == 1) { PB += R*cc[k] - I*ss[k];  QB += R*ss[k] + I*cc[k]; }
        else if (cls == 2) PC += R*cc[k] - I*ss[k];
        else               { PD += R*cc[k] - I*ss[k];  QD += R*ss[k] + I*cc[k]; }
      }
      const float T1 = PA + PC, T2 = PB + PD;
      const float T3 = PA - PC, T4 = QB - QD;
      const int cb = wl + g*32;
      out[ob + cb]       = (T1 + T2) * scale;
      out[ob + cb + 64]  = (T3 - T4) * scale;
      out[ob + cb + 128] = (T1 - T2) * scale;
      out[ob + cb + 192] = (T3 + T4) * scale;
    }
  }
}

extern "C" void kernel_launch(void* const* d_in, const int* in_sizes, int n_in,
                              void* d_out, int out_size, void* d_ws, size_t ws_size,
                              hipStream_t stream) {
  const float* x   = (const float*)d_in[0];
  const float* w1r = (const float*)d_in[1];
  const float* w1i = (const float*)d_in[2];
  const float* w2r = (const float*)d_in[3];
  const float* w2i = (const float*)d_in[4];
  float* out = (float*)d_out;
  float* ws  = (float*)d_ws;

  hipLaunchKernelGGL(k0_init,  dim3(47),    dim3(256), 0, stream, ws);
  hipLaunchKernelGGL(k12_dft,  dim3(256),   dim3(256), 0, stream, x, ws);
  hipLaunchKernelGGL(k3_mix,   dim3(64, 4), dim3(256), 0, stream, w1r, w1i, w2r, w2i, ws);
  hipLaunchKernelGGL(k45_idft, dim3(1024),  dim3(256), 0, stream, ws, out);
}